// Round 2
// baseline (700.163 us; speedup 1.0000x reference)
//
#include <hip/hip_runtime.h>

#define T_TOK 4096
#define H_DIM 1024
#define F_DIM 2816
#define E_NUM 8
#define EPSV 1e-5f

typedef unsigned short u16;
typedef __attribute__((ext_vector_type(8))) short bf16x8;
typedef __attribute__((ext_vector_type(4))) float f32x4;

__device__ __forceinline__ u16 f2bf(float f) {
  union { float f; unsigned u; } c; c.f = f;
  unsigned u = c.u;
  return (u16)((u + 0x7FFFu + ((u >> 16) & 1u)) >> 16);
}

// async 16B global->LDS; LDS dest is wave-uniform base + lane*16
__device__ __forceinline__ void llds16(const u16* g, u16* l) {
  __builtin_amdgcn_global_load_lds(
      (const __attribute__((address_space(1))) unsigned int*)g,
      (__attribute__((address_space(3))) unsigned int*)l, 16, 0, 0);
}

// ---------------- Router: RMSNorm + logits + softmax + top2 + gather lists ---
__global__ __launch_bounds__(256) void router_kernel(
    const float* __restrict__ hs, const float* __restrict__ lnw,
    const float* __restrict__ rw, u16* __restrict__ x_h,
    int* __restrict__ cnt, int* __restrict__ list,
    float* __restrict__ wcomb, int* __restrict__ slot) {
  const int wave = threadIdx.x >> 6;
  const int lane = threadIdx.x & 63;
  const int t = blockIdx.x * 4 + wave;
  const float* row = hs + (size_t)t * H_DIM;

  float4 v[4];
  float ss = 0.f;
#pragma unroll
  for (int j = 0; j < 4; ++j) {
    v[j] = ((const float4*)row)[j * 64 + lane];
    ss += v[j].x * v[j].x + v[j].y * v[j].y + v[j].z * v[j].z + v[j].w * v[j].w;
  }
#pragma unroll
  for (int m = 32; m; m >>= 1) ss += __shfl_xor(ss, m, 64);
  const float inv = rsqrtf(ss * (1.0f / H_DIM) + EPSV);

  float lg[E_NUM];
#pragma unroll
  for (int e = 0; e < E_NUM; ++e) lg[e] = 0.f;

#pragma unroll
  for (int j = 0; j < 4; ++j) {
    const int idx = j * 64 + lane;       // float4 index
    const int h0 = idx * 4;
    float4 w4 = ((const float4*)lnw)[idx];
    float xv[4] = {v[j].x * inv * w4.x, v[j].y * inv * w4.y,
                   v[j].z * inv * w4.z, v[j].w * inv * w4.w};
    ushort4 xs;
    xs.x = f2bf(xv[0]); xs.y = f2bf(xv[1]); xs.z = f2bf(xv[2]); xs.w = f2bf(xv[3]);
    ((ushort4*)(x_h + (size_t)t * H_DIM))[idx] = xs;
#pragma unroll
    for (int q = 0; q < 4; ++q) {
      const float* rr = rw + (size_t)(h0 + q) * E_NUM;
      float4 a = ((const float4*)rr)[0];
      float4 b = ((const float4*)rr)[1];
      lg[0] += xv[q] * a.x; lg[1] += xv[q] * a.y;
      lg[2] += xv[q] * a.z; lg[3] += xv[q] * a.w;
      lg[4] += xv[q] * b.x; lg[5] += xv[q] * b.y;
      lg[6] += xv[q] * b.z; lg[7] += xv[q] * b.w;
    }
  }
#pragma unroll
  for (int e = 0; e < E_NUM; ++e)
#pragma unroll
    for (int m = 32; m; m >>= 1) lg[e] += __shfl_xor(lg[e], m, 64);

  if (lane == 0) {
    float mx = lg[0];
#pragma unroll
    for (int e = 1; e < E_NUM; ++e) mx = fmaxf(mx, lg[e]);
    float p[E_NUM], s = 0.f;
#pragma unroll
    for (int e = 0; e < E_NUM; ++e) { p[e] = __expf(lg[e] - mx); s += p[e]; }
    const float invs = 1.0f / s;
    int e1 = 0; float b1 = p[0];
#pragma unroll
    for (int e = 1; e < E_NUM; ++e) if (p[e] > b1) { b1 = p[e]; e1 = e; }
    int e2 = -1; float b2 = -1.f;
#pragma unroll
    for (int e = 0; e < E_NUM; ++e) if (e != e1 && p[e] > b2) { b2 = p[e]; e2 = e; }
    b1 *= invs; b2 *= invs;
    int p1 = atomicAdd(&cnt[e1], 1);
    list[e1 * T_TOK + p1] = t; wcomb[e1 * T_TOK + p1] = b1;
    slot[2 * t] = (e1 << 16) | p1;
    int p2 = atomicAdd(&cnt[e2], 1);
    list[e2 * T_TOK + p2] = t; wcomb[e2 * T_TOK + p2] = b2;
    slot[2 * t + 1] = (e2 << 16) | p2;
  }
}

__global__ void offsets_kernel(const int* __restrict__ cnt, int* __restrict__ offs) {
  if (threadIdx.x == 0) {
    int s = 0;
    for (int e = 0; e < E_NUM; ++e) { offs[e] = s; s += cnt[e]; }
  }
}

// ---------------- merged wide transpose-convert: fp32 [R][C] -> bf16 [C][R] --
#define TPW 5632   // tiles per weight = E * (R/128) * (C/32), equal for all 3
__global__ __launch_bounds__(256) void transpose_cvt_all(
    const float* __restrict__ wg, const float* __restrict__ wu,
    const float* __restrict__ wd, u16* __restrict__ wgT,
    u16* __restrict__ wuT, u16* __restrict__ wdT) {
  __shared__ float tile[128][37];
  const int bx = blockIdx.x;
  const int which = bx / TPW;
  const int rem = bx - which * TPW;
  const int e = rem / 704;
  const int t = rem - e * 704;
  const float* in; u16* outp; int R, C, rt, ct;
  if (which == 0)      { in = wg; outp = wgT; R = H_DIM; C = F_DIM; rt = t / 88; ct = t - rt * 88; }
  else if (which == 1) { in = wu; outp = wuT; R = H_DIM; C = F_DIM; rt = t / 88; ct = t - rt * 88; }
  else                 { in = wd; outp = wdT; R = F_DIM; C = H_DIM; rt = t >> 5; ct = t & 31; }
  const size_t base = (size_t)e * R * C;
  const int r0 = rt * 128, c0 = ct * 32;
  const int tid = threadIdx.x;

  const int rr = tid >> 3, cq = tid & 7;
#pragma unroll
  for (int i = 0; i < 4; ++i) {
    float4 v = *(const float4*)(in + base + (size_t)(r0 + rr + 32 * i) * C + c0 + cq * 4);
    float* dst = &tile[rr + 32 * i][cq * 4];
    dst[0] = v.x; dst[1] = v.y; dst[2] = v.z; dst[3] = v.w;
  }
  __syncthreads();

  const int cc = tid >> 4, rq0 = tid & 15;
#pragma unroll
  for (int jj = 0; jj < 4; ++jj) {
    const int c = cc + 16 * (jj & 1);
    const int rq = rq0 + 16 * (jj >> 1);
    ushort4 o;
    o.x = f2bf(tile[rq * 4 + 0][c]);
    o.y = f2bf(tile[rq * 4 + 1][c]);
    o.z = f2bf(tile[rq * 4 + 2][c]);
    o.w = f2bf(tile[rq * 4 + 3][c]);
    *(ushort4*)(outp + base + (size_t)(c0 + c) * R + r0 + rq * 4) = o;
  }
}

// ---------------- Stage 1: h = silu(X Wg) * (X Wu), 256x(128F x {g,u}) tile --
// BM=256 tokens, BN=256 logical cols (16-col groups alternate gate/up so the
// silu pairing is within-lane: tn even=gate, tn odd=up, same F-col group).
// BK=32, 512 thr / 8 waves (2x4), dbuf LDS=64KB -> 2 blocks/CU.
// chunk swizzle: phys_chunk = chunk ^ ((row ^ (row>>2)) & 3)  (<=2-way, free)
__global__ __launch_bounds__(512, 2) void gemm1_kernel(
    const u16* __restrict__ x_h, const u16* __restrict__ wgT,
    const u16* __restrict__ wuT, const int* __restrict__ cnt,
    const int* __restrict__ offs, const int* __restrict__ list,
    u16* __restrict__ hbuf) {
  const int e = blockIdx.z;
  const int n_e = cnt[e];
  const int rt = blockIdx.y;
  if (rt * 256 >= n_e) return;
  const int ft = blockIdx.x;   // 128 F-cols per tile

  __shared__ __align__(16) u16 As[2][256 * 32];
  __shared__ __align__(16) u16 Bs[2][256 * 32];

  const int tid = threadIdx.x;
  const int wv = tid >> 6, lane = tid & 63;
  const int wm = wv >> 2, wn = wv & 3;
  const int lrow = lane & 15, quad = lane >> 4;

  // staging: per call, 64 lanes cover 16 rows x 4 chunks (16B each)
  const u16* agp[2]; const u16* bgp[2];
#pragma unroll
  for (int i = 0; i < 2; ++i) {
    const int r = (wv * 2 + i) * 16 + (lane >> 2);
    const int chunk = (lane & 3) ^ ((r ^ (r >> 2)) & 3);
    // A: gathered token rows
    int gr = rt * 256 + r; if (gr >= n_e) gr = n_e - 1;
    const int tkn = list[e * T_TOK + gr];
    agp[i] = x_h + (size_t)tkn * H_DIM + chunk * 8;
    // B: logical col r -> F-col + matrix select (bit4 of r)
    const int fcol = ft * 128 + ((r >> 5) << 4) + (r & 15);
    const u16* src = ((r >> 4) & 1) ? wuT : wgT;
    bgp[i] = src + ((size_t)e * F_DIM + fcol) * H_DIM + chunk * 8;
  }

  // fragment LDS element offsets
  int aoff[8], boff[4];
#pragma unroll
  for (int tm = 0; tm < 8; ++tm) {
    const int row = wm * 128 + tm * 16 + lrow;
    aoff[tm] = row * 32 + (((quad ^ (row ^ (row >> 2))) & 3) << 3);
  }
#pragma unroll
  for (int tn = 0; tn < 4; ++tn) {
    const int row = wn * 64 + tn * 16 + lrow;
    boff[tn] = row * 32 + (((quad ^ (row ^ (row >> 2))) & 3) << 3);
  }

  f32x4 acc[8][4];
#pragma unroll
  for (int i = 0; i < 8; ++i)
#pragma unroll
    for (int j = 0; j < 4; ++j) acc[i][j] = f32x4{0.f, 0.f, 0.f, 0.f};

  auto stage = [&](int b, int k0) {
#pragma unroll
    for (int i = 0; i < 2; ++i) {
      llds16(agp[i] + k0, &As[b][(wv * 2 + i) * 16 * 32]);
      llds16(bgp[i] + k0, &Bs[b][(wv * 2 + i) * 16 * 32]);
    }
  };
  auto compute = [&](int b) {
    bf16x8 a[8], bb[4];
#pragma unroll
    for (int tm = 0; tm < 8; ++tm) a[tm] = *(const bf16x8*)&As[b][aoff[tm]];
#pragma unroll
    for (int tn = 0; tn < 4; ++tn) bb[tn] = *(const bf16x8*)&Bs[b][boff[tn]];
#pragma unroll
    for (int tm = 0; tm < 8; ++tm)
#pragma unroll
      for (int tn = 0; tn < 4; ++tn)
        acc[tm][tn] = __builtin_amdgcn_mfma_f32_16x16x32_bf16(a[tm], bb[tn], acc[tm][tn], 0, 0, 0);
  };

  stage(0, 0);
#pragma unroll 1
  for (int k0 = 0; k0 < H_DIM; k0 += 64) {
    if (k0 + 32 < H_DIM) {
      stage(1, k0 + 32);
      asm volatile("s_waitcnt vmcnt(4)" ::: "memory");
    } else {
      asm volatile("s_waitcnt vmcnt(0)" ::: "memory");
    }
    __builtin_amdgcn_s_barrier();
    compute(0);
    __builtin_amdgcn_s_barrier();
    if (k0 + 64 < H_DIM) {
      stage(0, k0 + 64);
      asm volatile("s_waitcnt vmcnt(4)" ::: "memory");
    } else {
      asm volatile("s_waitcnt vmcnt(0)" ::: "memory");
    }
    __builtin_amdgcn_s_barrier();
    compute(1);
    __builtin_amdgcn_s_barrier();
  }

  const int oe = offs[e];
#pragma unroll
  for (int tm = 0; tm < 8; ++tm) {
    const int lr0 = wm * 128 + tm * 16 + quad * 4;
#pragma unroll
    for (int rr = 0; rr < 4; ++rr) {
      const int gr = rt * 256 + lr0 + rr;
      if (gr < n_e) {
#pragma unroll
        for (int p = 0; p < 2; ++p) {
          float g = acc[tm][2 * p][rr];
          float u = acc[tm][2 * p + 1][rr];
          float hv = g / (1.0f + __expf(-g)) * u;
          const int col = ft * 128 + (wn * 2 + p) * 16 + lrow;
          hbuf[(size_t)(oe + gr) * F_DIM + col] = f2bf(hv);
        }
      }
    }
  }
}

// ---------------- Stage 2: contrib = combine * (h Wd), 128x128 tile ----------
__global__ __launch_bounds__(256) void gemm2_kernel(
    const u16* __restrict__ hbuf, const u16* __restrict__ wdT,
    const int* __restrict__ cnt, const int* __restrict__ offs,
    const float* __restrict__ wcomb, float* __restrict__ contrib) {
  const int e = blockIdx.z;
  const int n_e = cnt[e];
  const int rt = blockIdx.y;
  if (rt * 128 >= n_e) return;
  const int nt = blockIdx.x;

  __shared__ __align__(16) u16 As[2][128 * 64];
  __shared__ __align__(16) u16 Bs[2][128 * 64];

  const int tid = threadIdx.x;
  const int oe = offs[e];
  const int wv = tid >> 6, lane = tid & 63;
  const int wm = wv >> 1, wn = wv & 1;
  const int lrow = lane & 15, quad = lane >> 4;
  const int srow = lane >> 3, schunk = lane & 7;

  const u16* agp[4];
#pragma unroll
  for (int i = 0; i < 4; ++i) {
    const int rl = wv * 32 + i * 8 + srow;
    int gr = rt * 128 + rl; if (gr >= n_e) gr = n_e - 1;
    agp[i] = hbuf + (size_t)(oe + gr) * F_DIM + ((schunk ^ (rl & 7)) << 3);
  }
  const size_t wb = ((size_t)e * H_DIM + (size_t)nt * 128) * F_DIM;
  const u16* bgp[4];
#pragma unroll
  for (int i = 0; i < 4; ++i) {
    const int r = wv * 32 + i * 8 + srow;
    bgp[i] = wdT + wb + (size_t)r * F_DIM + ((schunk ^ (r & 7)) << 3);
  }

  int aoff[4][2], boff[4][2];
#pragma unroll
  for (int tm = 0; tm < 4; ++tm) {
    const int row = wm * 64 + tm * 16 + lrow;
#pragma unroll
    for (int ks = 0; ks < 2; ++ks)
      aoff[tm][ks] = row * 64 + (((ks * 4 + quad) ^ (row & 7)) << 3);
  }
#pragma unroll
  for (int tn = 0; tn < 4; ++tn) {
    const int row = wn * 64 + tn * 16 + lrow;
#pragma unroll
    for (int ks = 0; ks < 2; ++ks)
      boff[tn][ks] = row * 64 + (((ks * 4 + quad) ^ (row & 7)) << 3);
  }

  f32x4 acc[4][4];
#pragma unroll
  for (int i = 0; i < 4; ++i)
#pragma unroll
    for (int j = 0; j < 4; ++j) acc[i][j] = f32x4{0.f, 0.f, 0.f, 0.f};

  auto stage = [&](int b, int k0) {
#pragma unroll
    for (int i = 0; i < 4; ++i) {
      llds16(agp[i] + k0, &As[b][(wv * 32 + i * 8) * 64]);
      llds16(bgp[i] + k0, &Bs[b][(wv * 32 + i * 8) * 64]);
    }
  };
  auto compute = [&](int b) {
#pragma unroll
    for (int ks = 0; ks < 2; ++ks) {
      bf16x8 a[4], bb[4];
#pragma unroll
      for (int tm = 0; tm < 4; ++tm) a[tm] = *(const bf16x8*)&As[b][aoff[tm][ks]];
#pragma unroll
      for (int tn = 0; tn < 4; ++tn) bb[tn] = *(const bf16x8*)&Bs[b][boff[tn][ks]];
#pragma unroll
      for (int tm = 0; tm < 4; ++tm)
#pragma unroll
        for (int tn = 0; tn < 4; ++tn)
          acc[tm][tn] = __builtin_amdgcn_mfma_f32_16x16x32_bf16(a[tm], bb[tn], acc[tm][tn], 0, 0, 0);
    }
  };

  stage(0, 0);
#pragma unroll 1
  for (int k0 = 0; k0 < F_DIM; k0 += 128) {
    const bool s1 = (k0 + 64) < F_DIM;
    if (s1) {
      stage(1, k0 + 64);
      asm volatile("s_waitcnt vmcnt(8)" ::: "memory");
    } else {
      asm volatile("s_waitcnt vmcnt(0)" ::: "memory");
    }
    __builtin_amdgcn_s_barrier();
    compute(0);
    __builtin_amdgcn_s_barrier();
    const bool s2 = (k0 + 128) < F_DIM;
    if (s2) {
      stage(0, k0 + 128);
      asm volatile("s_waitcnt vmcnt(8)" ::: "memory");
    } else {
      asm volatile("s_waitcnt vmcnt(0)" ::: "memory");
    }
    __builtin_amdgcn_s_barrier();
    compute(1);
    __builtin_amdgcn_s_barrier();
  }

#pragma unroll
  for (int tm = 0; tm < 4; ++tm) {
    const int lr0 = wm * 64 + tm * 16 + quad * 4;
#pragma unroll
    for (int rr = 0; rr < 4; ++rr) {
      const int gr = rt * 128 + lr0 + rr;
      if (gr < n_e) {
        const float cw = wcomb[e * T_TOK + gr];
#pragma unroll
        for (int tn = 0; tn < 4; ++tn) {
          const int col = nt * 128 + wn * 64 + tn * 16 + lrow;
          contrib[(size_t)(oe + gr) * H_DIM + col] = acc[tm][tn][rr] * cw;
        }
      }
    }
  }
}

// ---------------- Combine: out[t] = contrib[slot0] + contrib[slot1] ----------
__global__ __launch_bounds__(256) void combine_kernel(
    const float* __restrict__ contrib, const int* __restrict__ offs,
    const int* __restrict__ slot, float* __restrict__ out) {
  const int t = blockIdx.x;
  const int s0 = slot[2 * t], s1 = slot[2 * t + 1];
  const int r0 = offs[s0 >> 16] + (s0 & 0xFFFF);
  const int r1 = offs[s1 >> 16] + (s1 & 0xFFFF);
  float4 a = ((const float4*)(contrib + (size_t)r0 * H_DIM))[threadIdx.x];
  float4 b = ((const float4*)(contrib + (size_t)r1 * H_DIM))[threadIdx.x];
  float4 o = {a.x + b.x, a.y + b.y, a.z + b.z, a.w + b.w};
  ((float4*)(out + (size_t)t * H_DIM))[threadIdx.x] = o;
}

extern "C" void kernel_launch(void* const* d_in, const int* in_sizes, int n_in,
                              void* d_out, int out_size, void* d_ws, size_t ws_size,
                              hipStream_t stream) {
  const float* hs  = (const float*)d_in[0];
  const float* lnw = (const float*)d_in[1];
  const float* rw  = (const float*)d_in[2];
  const float* wg  = (const float*)d_in[3];
  const float* wu  = (const float*)d_in[4];
  const float* wd  = (const float*)d_in[5];
  float* out = (float*)d_out;

  char* p = (char*)d_ws;
  const size_t SZ_XH = (size_t)T_TOK * H_DIM * 2;          // 8 MB
  const size_t SZ_W  = (size_t)E_NUM * F_DIM * H_DIM * 2;  // 46 MB each
  const size_t SZ_HB = (size_t)T_TOK * 2 * F_DIM * 2;      // 46 MB
  const size_t SZ_CT = (size_t)T_TOK * 2 * H_DIM * 4;      // 33.5 MB

  u16* x_h  = (u16*)p;   p += SZ_XH;
  u16* wgT  = (u16*)p;   p += SZ_W;
  u16* wuT  = (u16*)p;   p += SZ_W;
  u16* wdT  = (u16*)p;   p += SZ_W;
  u16* hbuf = (u16*)p;   p += SZ_HB;
  float* contrib = (float*)p; p += SZ_CT;
  int* cnt  = (int*)p;   p += 256;
  int* offs = (int*)p;   p += 256;
  int* list = (int*)p;   p += (size_t)E_NUM * T_TOK * 4;
  float* wcomb = (float*)p; p += (size_t)E_NUM * T_TOK * 4;
  int* slot = (int*)p;   p += (size_t)T_TOK * 2 * 4;

  hipMemsetAsync(cnt, 0, 256, stream);
  router_kernel<<<T_TOK / 4, 256, 0, stream>>>(hs, lnw, rw, x_h, cnt, list, wcomb, slot);
  offsets_kernel<<<1, 64, 0, stream>>>(cnt, offs);
  transpose_cvt_all<<<3 * TPW, 256, 0, stream>>>(wg, wu, wd, wgT, wuT, wdT);
  gemm1_kernel<<<dim3(F_DIM / 128, T_TOK / 256, E_NUM), 512, 0, stream>>>(x_h, wgT, wuT, cnt, offs, list, hbuf);
  gemm2_kernel<<<dim3(H_DIM / 128, T_TOK / 128, E_NUM), 256, 0, stream>>>(hbuf, wdT, cnt, offs, wcomb, contrib);
  combine_kernel<<<T_TOK, 256, 0, stream>>>(contrib, offs, slot, out);
}

// Round 3
// 588.118 us; speedup vs baseline: 1.1905x; 1.1905x over previous
//
#include <hip/hip_runtime.h>

#define T_TOK 4096
#define H_DIM 1024
#define F_DIM 2816
#define E_NUM 8
#define EPSV 1e-5f
#define MAX_TILES 72

typedef unsigned short u16;
typedef __attribute__((ext_vector_type(8))) short bf16x8;
typedef __attribute__((ext_vector_type(4))) float f32x4;

__device__ __forceinline__ u16 f2bf(float f) {
  union { float f; unsigned u; } c; c.f = f;
  unsigned u = c.u;
  return (u16)((u + 0x7FFFu + ((u >> 16) & 1u)) >> 16);
}

// async 16B global->LDS; LDS dest is wave-uniform base + lane*16
__device__ __forceinline__ void llds16(const u16* g, u16* l) {
  __builtin_amdgcn_global_load_lds(
      (const __attribute__((address_space(1))) unsigned int*)g,
      (__attribute__((address_space(3))) unsigned int*)l, 16, 0, 0);
}

// ---------------- Router: RMSNorm + logits + softmax + top2 + gather lists ---
__global__ __launch_bounds__(256) void router_kernel(
    const float* __restrict__ hs, const float* __restrict__ lnw,
    const float* __restrict__ rw, u16* __restrict__ x_h,
    int* __restrict__ cnt, int* __restrict__ list,
    float* __restrict__ wcomb, int* __restrict__ slot) {
  const int wave = threadIdx.x >> 6;
  const int lane = threadIdx.x & 63;
  const int t = blockIdx.x * 4 + wave;
  const float* row = hs + (size_t)t * H_DIM;

  float4 v[4];
  float ss = 0.f;
#pragma unroll
  for (int j = 0; j < 4; ++j) {
    v[j] = ((const float4*)row)[j * 64 + lane];
    ss += v[j].x * v[j].x + v[j].y * v[j].y + v[j].z * v[j].z + v[j].w * v[j].w;
  }
#pragma unroll
  for (int m = 32; m; m >>= 1) ss += __shfl_xor(ss, m, 64);
  const float inv = rsqrtf(ss * (1.0f / H_DIM) + EPSV);

  float lg[E_NUM];
#pragma unroll
  for (int e = 0; e < E_NUM; ++e) lg[e] = 0.f;

#pragma unroll
  for (int j = 0; j < 4; ++j) {
    const int idx = j * 64 + lane;       // float4 index
    const int h0 = idx * 4;
    float4 w4 = ((const float4*)lnw)[idx];
    float xv[4] = {v[j].x * inv * w4.x, v[j].y * inv * w4.y,
                   v[j].z * inv * w4.z, v[j].w * inv * w4.w};
    ushort4 xs;
    xs.x = f2bf(xv[0]); xs.y = f2bf(xv[1]); xs.z = f2bf(xv[2]); xs.w = f2bf(xv[3]);
    ((ushort4*)(x_h + (size_t)t * H_DIM))[idx] = xs;
#pragma unroll
    for (int q = 0; q < 4; ++q) {
      const float* rr = rw + (size_t)(h0 + q) * E_NUM;
      float4 a = ((const float4*)rr)[0];
      float4 b = ((const float4*)rr)[1];
      lg[0] += xv[q] * a.x; lg[1] += xv[q] * a.y;
      lg[2] += xv[q] * a.z; lg[3] += xv[q] * a.w;
      lg[4] += xv[q] * b.x; lg[5] += xv[q] * b.y;
      lg[6] += xv[q] * b.z; lg[7] += xv[q] * b.w;
    }
  }
#pragma unroll
  for (int e = 0; e < E_NUM; ++e)
#pragma unroll
    for (int m = 32; m; m >>= 1) lg[e] += __shfl_xor(lg[e], m, 64);

  if (lane == 0) {
    float mx = lg[0];
#pragma unroll
    for (int e = 1; e < E_NUM; ++e) mx = fmaxf(mx, lg[e]);
    float p[E_NUM], s = 0.f;
#pragma unroll
    for (int e = 0; e < E_NUM; ++e) { p[e] = __expf(lg[e] - mx); s += p[e]; }
    const float invs = 1.0f / s;
    int e1 = 0; float b1 = p[0];
#pragma unroll
    for (int e = 1; e < E_NUM; ++e) if (p[e] > b1) { b1 = p[e]; e1 = e; }
    int e2 = -1; float b2 = -1.f;
#pragma unroll
    for (int e = 0; e < E_NUM; ++e) if (e != e1 && p[e] > b2) { b2 = p[e]; e2 = e; }
    b1 *= invs; b2 *= invs;
    int p1 = atomicAdd(&cnt[e1], 1);
    list[e1 * T_TOK + p1] = t; wcomb[e1 * T_TOK + p1] = b1;
    slot[2 * t] = (e1 << 16) | p1;
    int p2 = atomicAdd(&cnt[e2], 1);
    list[e2 * T_TOK + p2] = t; wcomb[e2 * T_TOK + p2] = b2;
    slot[2 * t + 1] = (e2 << 16) | p2;
  }
}

// offsets + compacted tile map: y-tile -> (expert, row-tile)
__global__ void offsets_kernel(const int* __restrict__ cnt, int* __restrict__ offs,
                               int* __restrict__ tmap) {
  if (threadIdx.x == 0) {
    int s = 0, ty = 0;
    for (int e = 0; e < E_NUM; ++e) {
      offs[e] = s; s += cnt[e];
      const int nt = (cnt[e] + 127) >> 7;
      for (int r = 0; r < nt; ++r) tmap[ty++] = (e << 16) | r;
    }
    for (; ty < MAX_TILES; ++ty) tmap[ty] = -1;
  }
}

// ---------------- merged wide transpose-convert: fp32 [R][C] -> bf16 [C][R] --
#define TPW 5632   // tiles per weight = E * (R/128) * (C/32), equal for all 3
__global__ __launch_bounds__(256) void transpose_cvt_all(
    const float* __restrict__ wg, const float* __restrict__ wu,
    const float* __restrict__ wd, u16* __restrict__ wgT,
    u16* __restrict__ wuT, u16* __restrict__ wdT) {
  __shared__ float tile[128][37];
  const int bx = blockIdx.x;
  const int which = bx / TPW;
  const int rem = bx - which * TPW;
  const int e = rem / 704;
  const int t = rem - e * 704;
  const float* in; u16* outp; int R, C, rt, ct;
  if (which == 0)      { in = wg; outp = wgT; R = H_DIM; C = F_DIM; rt = t / 88; ct = t - rt * 88; }
  else if (which == 1) { in = wu; outp = wuT; R = H_DIM; C = F_DIM; rt = t / 88; ct = t - rt * 88; }
  else                 { in = wd; outp = wdT; R = F_DIM; C = H_DIM; rt = t >> 5; ct = t & 31; }
  const size_t base = (size_t)e * R * C;
  const int r0 = rt * 128, c0 = ct * 32;
  const int tid = threadIdx.x;

  const int rr = tid >> 3, cq = tid & 7;
#pragma unroll
  for (int i = 0; i < 4; ++i) {
    float4 v = *(const float4*)(in + base + (size_t)(r0 + rr + 32 * i) * C + c0 + cq * 4);
    float* dst = &tile[rr + 32 * i][cq * 4];
    dst[0] = v.x; dst[1] = v.y; dst[2] = v.z; dst[3] = v.w;
  }
  __syncthreads();

  const int cc = tid >> 4, rq0 = tid & 15;
#pragma unroll
  for (int jj = 0; jj < 4; ++jj) {
    const int c = cc + 16 * (jj & 1);
    const int rq = rq0 + 16 * (jj >> 1);
    ushort4 o;
    o.x = f2bf(tile[rq * 4 + 0][c]);
    o.y = f2bf(tile[rq * 4 + 1][c]);
    o.z = f2bf(tile[rq * 4 + 2][c]);
    o.w = f2bf(tile[rq * 4 + 3][c]);
    *(ushort4*)(outp + base + (size_t)(c0 + c) * R + r0 + rq * 4) = o;
  }
}

// ---------------- Stage 1: h = silu(X Wg) * (X Wu), gathered rows ------------
// Single-buffered 32KB LDS (4 blocks/CU), compacted grid via tmap.
// LDS row-major [row][64] u16; 16B chunk c of row r at phys chunk c^(r&7).
__global__ __launch_bounds__(256, 4) void gemm1_kernel(
    const u16* __restrict__ x_h, const u16* __restrict__ wgT,
    const u16* __restrict__ wuT, const int* __restrict__ cnt,
    const int* __restrict__ offs, const int* __restrict__ list,
    const int* __restrict__ tmap, u16* __restrict__ hbuf) {
  const int tme = tmap[blockIdx.y];
  if (tme < 0) return;
  const int e = tme >> 16, rt = tme & 0xFFFF;
  const int n_e = cnt[e];
  const int ft = blockIdx.x;

  __shared__ __align__(16) u16 As[128 * 64];
  __shared__ __align__(16) u16 Bgs[64 * 64];
  __shared__ __align__(16) u16 Bus[64 * 64];

  const int tid = threadIdx.x;
  const int wv = tid >> 6, lane = tid & 63;
  const int wm = wv >> 1, wn = wv & 1;
  const int lrow = lane & 15, quad = lane >> 4;
  const int srow = lane >> 3, schunk = lane & 7;   // staging: 8 rows x 8 chunks

  // per-lane gather of token ids
  const u16* agp[4];
#pragma unroll
  for (int i = 0; i < 4; ++i) {
    const int rl = wv * 32 + i * 8 + srow;
    int gr = rt * 128 + rl; if (gr >= n_e) gr = n_e - 1;
    const int tkn = list[e * T_TOK + gr];
    agp[i] = x_h + (size_t)tkn * H_DIM + ((schunk ^ (rl & 7)) << 3);
  }
  const size_t wb = ((size_t)e * F_DIM + (size_t)ft * 64) * H_DIM;
  const u16* bgp[2]; const u16* bup[2];
#pragma unroll
  for (int i = 0; i < 2; ++i) {
    const int r = wv * 16 + i * 8 + srow;
    const size_t g = wb + (size_t)r * H_DIM + ((schunk ^ (r & 7)) << 3);
    bgp[i] = wgT + g;
    bup[i] = wuT + g;
  }

  // loop-invariant swizzled LDS element offsets
  int aoff[4][2], boff[2][2];
#pragma unroll
  for (int tm = 0; tm < 4; ++tm) {
    const int row = wm * 64 + tm * 16 + lrow;
#pragma unroll
    for (int ks = 0; ks < 2; ++ks)
      aoff[tm][ks] = row * 64 + (((ks * 4 + quad) ^ (row & 7)) << 3);
  }
#pragma unroll
  for (int tn = 0; tn < 2; ++tn) {
    const int row = wn * 32 + tn * 16 + lrow;
#pragma unroll
    for (int ks = 0; ks < 2; ++ks)
      boff[tn][ks] = row * 64 + (((ks * 4 + quad) ^ (row & 7)) << 3);
  }

  f32x4 accg[4][2], accu[4][2];
#pragma unroll
  for (int i = 0; i < 4; ++i)
#pragma unroll
    for (int j = 0; j < 2; ++j) {
      accg[i][j] = f32x4{0.f, 0.f, 0.f, 0.f};
      accu[i][j] = f32x4{0.f, 0.f, 0.f, 0.f};
    }

#pragma unroll 1
  for (int k0 = 0; k0 < H_DIM; k0 += 64) {
#pragma unroll
    for (int i = 0; i < 4; ++i)
      llds16(agp[i] + k0, &As[(wv * 32 + i * 8) * 64]);
#pragma unroll
    for (int i = 0; i < 2; ++i) {
      llds16(bgp[i] + k0, &Bgs[(wv * 16 + i * 8) * 64]);
      llds16(bup[i] + k0, &Bus[(wv * 16 + i * 8) * 64]);
    }
    __syncthreads();
#pragma unroll
    for (int ks = 0; ks < 2; ++ks) {
      bf16x8 a[4], bg[2], bu[2];
#pragma unroll
      for (int tm = 0; tm < 4; ++tm) a[tm] = *(const bf16x8*)&As[aoff[tm][ks]];
#pragma unroll
      for (int tn = 0; tn < 2; ++tn) {
        bg[tn] = *(const bf16x8*)&Bgs[boff[tn][ks]];
        bu[tn] = *(const bf16x8*)&Bus[boff[tn][ks]];
      }
#pragma unroll
      for (int tm = 0; tm < 4; ++tm)
#pragma unroll
        for (int tn = 0; tn < 2; ++tn) {
          accg[tm][tn] = __builtin_amdgcn_mfma_f32_16x16x32_bf16(a[tm], bg[tn], accg[tm][tn], 0, 0, 0);
          accu[tm][tn] = __builtin_amdgcn_mfma_f32_16x16x32_bf16(a[tm], bu[tn], accu[tm][tn], 0, 0, 0);
        }
    }
    __syncthreads();
  }

  const int oe = offs[e];
#pragma unroll
  for (int tm = 0; tm < 4; ++tm) {
    const int lr0 = wm * 64 + tm * 16 + quad * 4;
#pragma unroll
    for (int rr = 0; rr < 4; ++rr) {
      const int gr = rt * 128 + lr0 + rr;
      if (gr < n_e) {
#pragma unroll
        for (int tn = 0; tn < 2; ++tn) {
          float g = accg[tm][tn][rr];
          float u = accu[tm][tn][rr];
          float hv = g / (1.0f + __expf(-g)) * u;
          int col = ft * 64 + wn * 32 + tn * 16 + lrow;
          hbuf[(size_t)(oe + gr) * F_DIM + col] = f2bf(hv);
        }
      }
    }
  }
}

// ---------------- Stage 2: contrib = combine * (h Wd), 128x128 tile ----------
__global__ __launch_bounds__(256, 4) void gemm2_kernel(
    const u16* __restrict__ hbuf, const u16* __restrict__ wdT,
    const int* __restrict__ cnt, const int* __restrict__ offs,
    const float* __restrict__ wcomb, const int* __restrict__ tmap,
    float* __restrict__ contrib) {
  const int tme = tmap[blockIdx.y];
  if (tme < 0) return;
  const int e = tme >> 16, rt = tme & 0xFFFF;
  const int n_e = cnt[e];
  const int nt = blockIdx.x;

  __shared__ __align__(16) u16 As[128 * 64];
  __shared__ __align__(16) u16 Bs[128 * 64];

  const int tid = threadIdx.x;
  const int oe = offs[e];
  const int wv = tid >> 6, lane = tid & 63;
  const int wm = wv >> 1, wn = wv & 1;
  const int lrow = lane & 15, quad = lane >> 4;
  const int srow = lane >> 3, schunk = lane & 7;

  const u16* agp[4];
#pragma unroll
  for (int i = 0; i < 4; ++i) {
    const int rl = wv * 32 + i * 8 + srow;
    int gr = rt * 128 + rl; if (gr >= n_e) gr = n_e - 1;
    agp[i] = hbuf + (size_t)(oe + gr) * F_DIM + ((schunk ^ (rl & 7)) << 3);
  }
  const size_t wb = ((size_t)e * H_DIM + (size_t)nt * 128) * F_DIM;
  const u16* bgp[4];
#pragma unroll
  for (int i = 0; i < 4; ++i) {
    const int r = wv * 32 + i * 8 + srow;
    bgp[i] = wdT + wb + (size_t)r * F_DIM + ((schunk ^ (r & 7)) << 3);
  }

  int aoff[4][2], boff[4][2];
#pragma unroll
  for (int tm = 0; tm < 4; ++tm) {
    const int row = wm * 64 + tm * 16 + lrow;
#pragma unroll
    for (int ks = 0; ks < 2; ++ks)
      aoff[tm][ks] = row * 64 + (((ks * 4 + quad) ^ (row & 7)) << 3);
  }
#pragma unroll
  for (int tn = 0; tn < 4; ++tn) {
    const int row = wn * 64 + tn * 16 + lrow;
#pragma unroll
    for (int ks = 0; ks < 2; ++ks)
      boff[tn][ks] = row * 64 + (((ks * 4 + quad) ^ (row & 7)) << 3);
  }

  f32x4 acc[4][4];
#pragma unroll
  for (int i = 0; i < 4; ++i)
#pragma unroll
    for (int j = 0; j < 4; ++j) acc[i][j] = f32x4{0.f, 0.f, 0.f, 0.f};

#pragma unroll 1
  for (int k0 = 0; k0 < F_DIM; k0 += 64) {
#pragma unroll
    for (int i = 0; i < 4; ++i) {
      llds16(agp[i] + k0, &As[(wv * 32 + i * 8) * 64]);
      llds16(bgp[i] + k0, &Bs[(wv * 32 + i * 8) * 64]);
    }
    __syncthreads();
#pragma unroll
    for (int ks = 0; ks < 2; ++ks) {
      bf16x8 a[4], bb[4];
#pragma unroll
      for (int tm = 0; tm < 4; ++tm) a[tm] = *(const bf16x8*)&As[aoff[tm][ks]];
#pragma unroll
      for (int tn = 0; tn < 4; ++tn) bb[tn] = *(const bf16x8*)&Bs[boff[tn][ks]];
#pragma unroll
      for (int tm = 0; tm < 4; ++tm)
#pragma unroll
        for (int tn = 0; tn < 4; ++tn)
          acc[tm][tn] = __builtin_amdgcn_mfma_f32_16x16x32_bf16(a[tm], bb[tn], acc[tm][tn], 0, 0, 0);
    }
    __syncthreads();
  }

#pragma unroll
  for (int tm = 0; tm < 4; ++tm) {
    const int lr0 = wm * 64 + tm * 16 + quad * 4;
#pragma unroll
    for (int rr = 0; rr < 4; ++rr) {
      const int gr = rt * 128 + lr0 + rr;
      if (gr < n_e) {
        const float cw = wcomb[e * T_TOK + gr];
#pragma unroll
        for (int tn = 0; tn < 4; ++tn) {
          const int col = nt * 128 + wn * 64 + tn * 16 + lrow;
          contrib[(size_t)(oe + gr) * H_DIM + col] = acc[tm][tn][rr] * cw;
        }
      }
    }
  }
}

// ---------------- Combine: out[t] = contrib[slot0] + contrib[slot1] ----------
__global__ __launch_bounds__(256) void combine_kernel(
    const float* __restrict__ contrib, const int* __restrict__ offs,
    const int* __restrict__ slot, float* __restrict__ out) {
  const int t = blockIdx.x;
  const int s0 = slot[2 * t], s1 = slot[2 * t + 1];
  const int r0 = offs[s0 >> 16] + (s0 & 0xFFFF);
  const int r1 = offs[s1 >> 16] + (s1 & 0xFFFF);
  float4 a = ((const float4*)(contrib + (size_t)r0 * H_DIM))[threadIdx.x];
  float4 b = ((const float4*)(contrib + (size_t)r1 * H_DIM))[threadIdx.x];
  float4 o = {a.x + b.x, a.y + b.y, a.z + b.z, a.w + b.w};
  ((float4*)(out + (size_t)t * H_DIM))[threadIdx.x] = o;
}

extern "C" void kernel_launch(void* const* d_in, const int* in_sizes, int n_in,
                              void* d_out, int out_size, void* d_ws, size_t ws_size,
                              hipStream_t stream) {
  const float* hs  = (const float*)d_in[0];
  const float* lnw = (const float*)d_in[1];
  const float* rw  = (const float*)d_in[2];
  const float* wg  = (const float*)d_in[3];
  const float* wu  = (const float*)d_in[4];
  const float* wd  = (const float*)d_in[5];
  float* out = (float*)d_out;

  char* p = (char*)d_ws;
  const size_t SZ_XH = (size_t)T_TOK * H_DIM * 2;          // 8 MB
  const size_t SZ_W  = (size_t)E_NUM * F_DIM * H_DIM * 2;  // 46 MB each
  const size_t SZ_HB = (size_t)T_TOK * 2 * F_DIM * 2;      // 46 MB
  const size_t SZ_CT = (size_t)T_TOK * 2 * H_DIM * 4;      // 33.5 MB

  u16* x_h  = (u16*)p;   p += SZ_XH;
  u16* wgT  = (u16*)p;   p += SZ_W;
  u16* wuT  = (u16*)p;   p += SZ_W;
  u16* wdT  = (u16*)p;   p += SZ_W;
  u16* hbuf = (u16*)p;   p += SZ_HB;
  float* contrib = (float*)p; p += SZ_CT;
  int* cnt  = (int*)p;   p += 256;
  int* offs = (int*)p;   p += 256;
  int* tmap = (int*)p;   p += 512;
  int* list = (int*)p;   p += (size_t)E_NUM * T_TOK * 4;
  float* wcomb = (float*)p; p += (size_t)E_NUM * T_TOK * 4;
  int* slot = (int*)p;   p += (size_t)T_TOK * 2 * 4;

  hipMemsetAsync(cnt, 0, 256, stream);
  router_kernel<<<T_TOK / 4, 256, 0, stream>>>(hs, lnw, rw, x_h, cnt, list, wcomb, slot);
  offsets_kernel<<<1, 64, 0, stream>>>(cnt, offs, tmap);
  transpose_cvt_all<<<3 * TPW, 256, 0, stream>>>(wg, wu, wd, wgT, wuT, wdT);
  gemm1_kernel<<<dim3(F_DIM / 64, MAX_TILES), 256, 0, stream>>>(x_h, wgT, wuT, cnt, offs, list, tmap, hbuf);
  gemm2_kernel<<<dim3(H_DIM / 128, MAX_TILES), 256, 0, stream>>>(hbuf, wdT, cnt, offs, wcomb, tmap, contrib);
  combine_kernel<<<T_TOK, 256, 0, stream>>>(contrib, offs, slot, out);
}

// Round 4
// 587.837 us; speedup vs baseline: 1.1911x; 1.0005x over previous
//
#include <hip/hip_runtime.h>

#define T_TOK 4096
#define H_DIM 1024
#define F_DIM 2816
#define E_NUM 8
#define EPSV 1e-5f
#define MAX_TILES 72

typedef unsigned short u16;
typedef __attribute__((ext_vector_type(8))) short bf16x8;
typedef __attribute__((ext_vector_type(8))) unsigned short u16x8;
typedef __attribute__((ext_vector_type(4))) float f32x4;

__device__ __forceinline__ u16 f2bf(float f) {
  union { float f; unsigned u; } c; c.f = f;
  unsigned u = c.u;
  return (u16)((u + 0x7FFFu + ((u >> 16) & 1u)) >> 16);
}

// async 16B global->LDS; LDS dest is wave-uniform base + lane*16
__device__ __forceinline__ void llds16(const u16* g, u16* l) {
  __builtin_amdgcn_global_load_lds(
      (const __attribute__((address_space(1))) unsigned int*)g,
      (__attribute__((address_space(3))) unsigned int*)l, 16, 0, 0);
}

// ---------------- Router: RMSNorm + logits + softmax + top2 + gather lists ---
__global__ __launch_bounds__(256) void router_kernel(
    const float* __restrict__ hs, const float* __restrict__ lnw,
    const float* __restrict__ rw, u16* __restrict__ x_h,
    int* __restrict__ cnt, int* __restrict__ list,
    float* __restrict__ wcomb, int* __restrict__ slot) {
  const int wave = threadIdx.x >> 6;
  const int lane = threadIdx.x & 63;
  const int t = blockIdx.x * 4 + wave;
  const float* row = hs + (size_t)t * H_DIM;

  float4 v[4];
  float ss = 0.f;
#pragma unroll
  for (int j = 0; j < 4; ++j) {
    v[j] = ((const float4*)row)[j * 64 + lane];
    ss += v[j].x * v[j].x + v[j].y * v[j].y + v[j].z * v[j].z + v[j].w * v[j].w;
  }
#pragma unroll
  for (int m = 32; m; m >>= 1) ss += __shfl_xor(ss, m, 64);
  const float inv = rsqrtf(ss * (1.0f / H_DIM) + EPSV);

  float lg[E_NUM];
#pragma unroll
  for (int e = 0; e < E_NUM; ++e) lg[e] = 0.f;

#pragma unroll
  for (int j = 0; j < 4; ++j) {
    const int idx = j * 64 + lane;       // float4 index
    const int h0 = idx * 4;
    float4 w4 = ((const float4*)lnw)[idx];
    float xv[4] = {v[j].x * inv * w4.x, v[j].y * inv * w4.y,
                   v[j].z * inv * w4.z, v[j].w * inv * w4.w};
    ushort4 xs;
    xs.x = f2bf(xv[0]); xs.y = f2bf(xv[1]); xs.z = f2bf(xv[2]); xs.w = f2bf(xv[3]);
    ((ushort4*)(x_h + (size_t)t * H_DIM))[idx] = xs;
#pragma unroll
    for (int q = 0; q < 4; ++q) {
      const float* rr = rw + (size_t)(h0 + q) * E_NUM;
      float4 a = ((const float4*)rr)[0];
      float4 b = ((const float4*)rr)[1];
      lg[0] += xv[q] * a.x; lg[1] += xv[q] * a.y;
      lg[2] += xv[q] * a.z; lg[3] += xv[q] * a.w;
      lg[4] += xv[q] * b.x; lg[5] += xv[q] * b.y;
      lg[6] += xv[q] * b.z; lg[7] += xv[q] * b.w;
    }
  }
#pragma unroll
  for (int e = 0; e < E_NUM; ++e)
#pragma unroll
    for (int m = 32; m; m >>= 1) lg[e] += __shfl_xor(lg[e], m, 64);

  if (lane == 0) {
    float mx = lg[0];
#pragma unroll
    for (int e = 1; e < E_NUM; ++e) mx = fmaxf(mx, lg[e]);
    float p[E_NUM], s = 0.f;
#pragma unroll
    for (int e = 0; e < E_NUM; ++e) { p[e] = __expf(lg[e] - mx); s += p[e]; }
    const float invs = 1.0f / s;
    int e1 = 0; float b1 = p[0];
#pragma unroll
    for (int e = 1; e < E_NUM; ++e) if (p[e] > b1) { b1 = p[e]; e1 = e; }
    int e2 = -1; float b2 = -1.f;
#pragma unroll
    for (int e = 0; e < E_NUM; ++e) if (e != e1 && p[e] > b2) { b2 = p[e]; e2 = e; }
    b1 *= invs; b2 *= invs;
    int p1 = atomicAdd(&cnt[e1], 1);
    list[e1 * T_TOK + p1] = t; wcomb[e1 * T_TOK + p1] = b1;
    slot[2 * t] = (e1 << 16) | p1;
    int p2 = atomicAdd(&cnt[e2], 1);
    list[e2 * T_TOK + p2] = t; wcomb[e2 * T_TOK + p2] = b2;
    slot[2 * t + 1] = (e2 << 16) | p2;
  }
}

// ---------------- merged wide transpose-convert: fp32 [R][C] -> bf16 [C][R] --
// 128r x 64c tiles, 8 in-flight float4 reads/thread, ushort8 (16B) stores.
// Block 0 also computes offsets + compacted tile map (cnt ready: runs after router).
#define TPW2 2816   // tiles per weight = E * (R/128) * (C/64), equal for all 3
__global__ __launch_bounds__(256) void transpose_cvt_all(
    const float* __restrict__ wg, const float* __restrict__ wu,
    const float* __restrict__ wd, u16* __restrict__ wgT,
    u16* __restrict__ wuT, u16* __restrict__ wdT,
    const int* __restrict__ cnt, int* __restrict__ offs,
    int* __restrict__ tmap) {
  if (blockIdx.x == 0 && threadIdx.x == 0) {
    int s = 0, ty = 0;
    for (int e = 0; e < E_NUM; ++e) {
      offs[e] = s; s += cnt[e];
      const int nt = (cnt[e] + 127) >> 7;
      for (int r = 0; r < nt; ++r) tmap[ty++] = (e << 16) | r;
    }
    for (; ty < MAX_TILES; ++ty) tmap[ty] = -1;
  }

  __shared__ float tile[128][65];
  const int bx = blockIdx.x;
  const int which = bx / TPW2;
  const int rem = bx - which * TPW2;
  const int e = rem / 352;
  const int t = rem - e * 352;
  const float* in; u16* outp; int R, C, rt, ct;
  if (which == 0)      { in = wg; outp = wgT; R = H_DIM; C = F_DIM; rt = t / 44; ct = t - rt * 44; }
  else if (which == 1) { in = wu; outp = wuT; R = H_DIM; C = F_DIM; rt = t / 44; ct = t - rt * 44; }
  else                 { in = wd; outp = wdT; R = F_DIM; C = H_DIM; rt = t >> 4; ct = t & 15; }
  const size_t base = (size_t)e * R * C;
  const int r0 = rt * 128, c0 = ct * 64;
  const int tid = threadIdx.x;

  // read: 8 x float4, rows it*16+(tid>>4), 16 chunks/row -> 256B runs
  const int rrow = tid >> 4, chunk = tid & 15;
  float4 v[8];
#pragma unroll
  for (int it = 0; it < 8; ++it) {
    const int r = it * 16 + rrow;
    v[it] = *(const float4*)(in + base + (size_t)(r0 + r) * C + c0 + chunk * 4);
  }
#pragma unroll
  for (int it = 0; it < 8; ++it) {
    float* dst = &tile[it * 16 + rrow][chunk * 4];
    dst[0] = v[it].x; dst[1] = v[it].y; dst[2] = v[it].z; dst[3] = v[it].w;
  }
  __syncthreads();

  // write: 4 x ushort8 (16B), out-row segments 256B contiguous
  const int cc = tid >> 4, rq = tid & 15;
#pragma unroll
  for (int it = 0; it < 4; ++it) {
    const int c = it * 16 + cc;
    u16x8 o;
#pragma unroll
    for (int j = 0; j < 8; ++j) o[j] = f2bf(tile[rq * 8 + j][c]);
    *(u16x8*)(outp + base + (size_t)(c0 + c) * R + r0 + rq * 8) = o;
  }
}

// ---------------- Stage 1: h = silu(X Wg) * (X Wu), gathered rows ------------
// Single-buffered 32KB LDS (4 blocks/CU), compacted grid via tmap.
// LDS row-major [row][64] u16; 16B chunk c of row r at phys chunk c^(r&7).
__global__ __launch_bounds__(256, 4) void gemm1_kernel(
    const u16* __restrict__ x_h, const u16* __restrict__ wgT,
    const u16* __restrict__ wuT, const int* __restrict__ cnt,
    const int* __restrict__ offs, const int* __restrict__ list,
    const int* __restrict__ tmap, u16* __restrict__ hbuf) {
  const int tme = tmap[blockIdx.y];
  if (tme < 0) return;
  const int e = tme >> 16, rt = tme & 0xFFFF;
  const int n_e = cnt[e];
  const int ft = blockIdx.x;

  __shared__ __align__(16) u16 As[128 * 64];
  __shared__ __align__(16) u16 Bgs[64 * 64];
  __shared__ __align__(16) u16 Bus[64 * 64];

  const int tid = threadIdx.x;
  const int wv = tid >> 6, lane = tid & 63;
  const int wm = wv >> 1, wn = wv & 1;
  const int lrow = lane & 15, quad = lane >> 4;
  const int srow = lane >> 3, schunk = lane & 7;   // staging: 8 rows x 8 chunks

  // per-lane gather of token ids
  const u16* agp[4];
#pragma unroll
  for (int i = 0; i < 4; ++i) {
    const int rl = wv * 32 + i * 8 + srow;
    int gr = rt * 128 + rl; if (gr >= n_e) gr = n_e - 1;
    const int tkn = list[e * T_TOK + gr];
    agp[i] = x_h + (size_t)tkn * H_DIM + ((schunk ^ (rl & 7)) << 3);
  }
  const size_t wb = ((size_t)e * F_DIM + (size_t)ft * 64) * H_DIM;
  const u16* bgp[2]; const u16* bup[2];
#pragma unroll
  for (int i = 0; i < 2; ++i) {
    const int r = wv * 16 + i * 8 + srow;
    const size_t g = wb + (size_t)r * H_DIM + ((schunk ^ (r & 7)) << 3);
    bgp[i] = wgT + g;
    bup[i] = wuT + g;
  }

  // loop-invariant swizzled LDS element offsets
  int aoff[4][2], boff[2][2];
#pragma unroll
  for (int tm = 0; tm < 4; ++tm) {
    const int row = wm * 64 + tm * 16 + lrow;
#pragma unroll
    for (int ks = 0; ks < 2; ++ks)
      aoff[tm][ks] = row * 64 + (((ks * 4 + quad) ^ (row & 7)) << 3);
  }
#pragma unroll
  for (int tn = 0; tn < 2; ++tn) {
    const int row = wn * 32 + tn * 16 + lrow;
#pragma unroll
    for (int ks = 0; ks < 2; ++ks)
      boff[tn][ks] = row * 64 + (((ks * 4 + quad) ^ (row & 7)) << 3);
  }

  f32x4 accg[4][2], accu[4][2];
#pragma unroll
  for (int i = 0; i < 4; ++i)
#pragma unroll
    for (int j = 0; j < 2; ++j) {
      accg[i][j] = f32x4{0.f, 0.f, 0.f, 0.f};
      accu[i][j] = f32x4{0.f, 0.f, 0.f, 0.f};
    }

#pragma unroll 1
  for (int k0 = 0; k0 < H_DIM; k0 += 64) {
#pragma unroll
    for (int i = 0; i < 4; ++i)
      llds16(agp[i] + k0, &As[(wv * 32 + i * 8) * 64]);
#pragma unroll
    for (int i = 0; i < 2; ++i) {
      llds16(bgp[i] + k0, &Bgs[(wv * 16 + i * 8) * 64]);
      llds16(bup[i] + k0, &Bus[(wv * 16 + i * 8) * 64]);
    }
    __syncthreads();
#pragma unroll
    for (int ks = 0; ks < 2; ++ks) {
      bf16x8 a[4], bg[2], bu[2];
#pragma unroll
      for (int tm = 0; tm < 4; ++tm) a[tm] = *(const bf16x8*)&As[aoff[tm][ks]];
#pragma unroll
      for (int tn = 0; tn < 2; ++tn) {
        bg[tn] = *(const bf16x8*)&Bgs[boff[tn][ks]];
        bu[tn] = *(const bf16x8*)&Bus[boff[tn][ks]];
      }
#pragma unroll
      for (int tm = 0; tm < 4; ++tm)
#pragma unroll
        for (int tn = 0; tn < 2; ++tn) {
          accg[tm][tn] = __builtin_amdgcn_mfma_f32_16x16x32_bf16(a[tm], bg[tn], accg[tm][tn], 0, 0, 0);
          accu[tm][tn] = __builtin_amdgcn_mfma_f32_16x16x32_bf16(a[tm], bu[tn], accu[tm][tn], 0, 0, 0);
        }
    }
    __syncthreads();
  }

  const int oe = offs[e];
#pragma unroll
  for (int tm = 0; tm < 4; ++tm) {
    const int lr0 = wm * 64 + tm * 16 + quad * 4;
#pragma unroll
    for (int rr = 0; rr < 4; ++rr) {
      const int gr = rt * 128 + lr0 + rr;
      if (gr < n_e) {
#pragma unroll
        for (int tn = 0; tn < 2; ++tn) {
          float g = accg[tm][tn][rr];
          float u = accu[tm][tn][rr];
          float hv = g / (1.0f + __expf(-g)) * u;
          int col = ft * 64 + wn * 32 + tn * 16 + lrow;
          hbuf[(size_t)(oe + gr) * F_DIM + col] = f2bf(hv);
        }
      }
    }
  }
}

// ---------------- Stage 2: contrib = combine * (h Wd), 128x64 tile ----------
__global__ __launch_bounds__(256, 4) void gemm2_kernel(
    const u16* __restrict__ hbuf, const u16* __restrict__ wdT,
    const int* __restrict__ cnt, const int* __restrict__ offs,
    const float* __restrict__ wcomb, const int* __restrict__ tmap,
    float* __restrict__ contrib) {
  const int tme = tmap[blockIdx.y];
  if (tme < 0) return;
  const int e = tme >> 16, rt = tme & 0xFFFF;
  const int n_e = cnt[e];
  const int nt = blockIdx.x;

  __shared__ __align__(16) u16 As[128 * 64];
  __shared__ __align__(16) u16 Bs[64 * 64];

  const int tid = threadIdx.x;
  const int oe = offs[e];
  const int wv = tid >> 6, lane = tid & 63;
  const int wm = wv >> 1, wn = wv & 1;
  const int lrow = lane & 15, quad = lane >> 4;
  const int srow = lane >> 3, schunk = lane & 7;

  const u16* agp[4];
#pragma unroll
  for (int i = 0; i < 4; ++i) {
    const int rl = wv * 32 + i * 8 + srow;
    int gr = rt * 128 + rl; if (gr >= n_e) gr = n_e - 1;
    agp[i] = hbuf + (size_t)(oe + gr) * F_DIM + ((schunk ^ (rl & 7)) << 3);
  }
  const size_t wb = ((size_t)e * H_DIM + (size_t)nt * 64) * F_DIM;
  const u16* bgp[2];
#pragma unroll
  for (int i = 0; i < 2; ++i) {
    const int r = wv * 16 + i * 8 + srow;
    bgp[i] = wdT + wb + (size_t)r * F_DIM + ((schunk ^ (r & 7)) << 3);
  }

  int aoff[4][2], boff[2][2];
#pragma unroll
  for (int tm = 0; tm < 4; ++tm) {
    const int row = wm * 64 + tm * 16 + lrow;
#pragma unroll
    for (int ks = 0; ks < 2; ++ks)
      aoff[tm][ks] = row * 64 + (((ks * 4 + quad) ^ (row & 7)) << 3);
  }
#pragma unroll
  for (int tn = 0; tn < 2; ++tn) {
    const int row = wn * 32 + tn * 16 + lrow;
#pragma unroll
    for (int ks = 0; ks < 2; ++ks)
      boff[tn][ks] = row * 64 + (((ks * 4 + quad) ^ (row & 7)) << 3);
  }

  f32x4 acc[4][2];
#pragma unroll
  for (int i = 0; i < 4; ++i)
#pragma unroll
    for (int j = 0; j < 2; ++j) acc[i][j] = f32x4{0.f, 0.f, 0.f, 0.f};

#pragma unroll 1
  for (int k0 = 0; k0 < F_DIM; k0 += 64) {
#pragma unroll
    for (int i = 0; i < 4; ++i)
      llds16(agp[i] + k0, &As[(wv * 32 + i * 8) * 64]);
#pragma unroll
    for (int i = 0; i < 2; ++i)
      llds16(bgp[i] + k0, &Bs[(wv * 16 + i * 8) * 64]);
    __syncthreads();
#pragma unroll
    for (int ks = 0; ks < 2; ++ks) {
      bf16x8 a[4], bb[2];
#pragma unroll
      for (int tm = 0; tm < 4; ++tm) a[tm] = *(const bf16x8*)&As[aoff[tm][ks]];
#pragma unroll
      for (int tn = 0; tn < 2; ++tn) bb[tn] = *(const bf16x8*)&Bs[boff[tn][ks]];
#pragma unroll
      for (int tm = 0; tm < 4; ++tm)
#pragma unroll
        for (int tn = 0; tn < 2; ++tn)
          acc[tm][tn] = __builtin_amdgcn_mfma_f32_16x16x32_bf16(a[tm], bb[tn], acc[tm][tn], 0, 0, 0);
    }
    __syncthreads();
  }

#pragma unroll
  for (int tm = 0; tm < 4; ++tm) {
    const int lr0 = wm * 64 + tm * 16 + quad * 4;
#pragma unroll
    for (int rr = 0; rr < 4; ++rr) {
      const int gr = rt * 128 + lr0 + rr;
      if (gr < n_e) {
        const float cw = wcomb[e * T_TOK + gr];
#pragma unroll
        for (int tn = 0; tn < 2; ++tn) {
          const int col = nt * 64 + wn * 32 + tn * 16 + lrow;
          contrib[(size_t)(oe + gr) * H_DIM + col] = acc[tm][tn][rr] * cw;
        }
      }
    }
  }
}

// ---------------- Combine: out[t] = contrib[slot0] + contrib[slot1] ----------
__global__ __launch_bounds__(256) void combine_kernel(
    const float* __restrict__ contrib, const int* __restrict__ offs,
    const int* __restrict__ slot, float* __restrict__ out) {
  const int t = blockIdx.x;
  const int s0 = slot[2 * t], s1 = slot[2 * t + 1];
  const int r0 = offs[s0 >> 16] + (s0 & 0xFFFF);
  const int r1 = offs[s1 >> 16] + (s1 & 0xFFFF);
  float4 a = ((const float4*)(contrib + (size_t)r0 * H_DIM))[threadIdx.x];
  float4 b = ((const float4*)(contrib + (size_t)r1 * H_DIM))[threadIdx.x];
  float4 o = {a.x + b.x, a.y + b.y, a.z + b.z, a.w + b.w};
  ((float4*)(out + (size_t)t * H_DIM))[threadIdx.x] = o;
}

extern "C" void kernel_launch(void* const* d_in, const int* in_sizes, int n_in,
                              void* d_out, int out_size, void* d_ws, size_t ws_size,
                              hipStream_t stream) {
  const float* hs  = (const float*)d_in[0];
  const float* lnw = (const float*)d_in[1];
  const float* rw  = (const float*)d_in[2];
  const float* wg  = (const float*)d_in[3];
  const float* wu  = (const float*)d_in[4];
  const float* wd  = (const float*)d_in[5];
  float* out = (float*)d_out;

  char* p = (char*)d_ws;
  const size_t SZ_XH = (size_t)T_TOK * H_DIM * 2;          // 8 MB
  const size_t SZ_W  = (size_t)E_NUM * F_DIM * H_DIM * 2;  // 46 MB each
  const size_t SZ_HB = (size_t)T_TOK * 2 * F_DIM * 2;      // 46 MB
  const size_t SZ_CT = (size_t)T_TOK * 2 * H_DIM * 4;      // 33.5 MB

  u16* x_h  = (u16*)p;   p += SZ_XH;
  u16* wgT  = (u16*)p;   p += SZ_W;
  u16* wuT  = (u16*)p;   p += SZ_W;
  u16* wdT  = (u16*)p;   p += SZ_W;
  u16* hbuf = (u16*)p;   p += SZ_HB;
  float* contrib = (float*)p; p += SZ_CT;
  int* cnt  = (int*)p;   p += 256;
  int* offs = (int*)p;   p += 256;
  int* tmap = (int*)p;   p += 512;
  int* list = (int*)p;   p += (size_t)E_NUM * T_TOK * 4;
  float* wcomb = (float*)p; p += (size_t)E_NUM * T_TOK * 4;
  int* slot = (int*)p;   p += (size_t)T_TOK * 2 * 4;

  hipMemsetAsync(cnt, 0, 256, stream);
  router_kernel<<<T_TOK / 4, 256, 0, stream>>>(hs, lnw, rw, x_h, cnt, list, wcomb, slot);
  transpose_cvt_all<<<3 * TPW2, 256, 0, stream>>>(wg, wu, wd, wgT, wuT, wdT, cnt, offs, tmap);
  gemm1_kernel<<<dim3(F_DIM / 64, MAX_TILES), 256, 0, stream>>>(x_h, wgT, wuT, cnt, offs, list, tmap, hbuf);
  gemm2_kernel<<<dim3(H_DIM / 64, MAX_TILES), 256, 0, stream>>>(hbuf, wdT, cnt, offs, wcomb, tmap, contrib);
  combine_kernel<<<T_TOK, 256, 0, stream>>>(contrib, offs, slot, out);
}